// Round 1
// baseline (703.009 us; speedup 1.0000x reference)
//
#include <hip/hip_runtime.h>
#include <hip/hip_bf16.h>

#define T_ 1024
#define H_ 1024
#define I_ 512
#define E_ 64
#define S_ 2
#define NJOB 66              // 64 routed + 2 shared "jobs"
#define KSEL 8
#define GRP 8
#define GSIZE 8              // experts per group
#define TKG 4                // topk_group
#define ROWS_TOTAL (T_*KSEL + S_*T_)   // 10240

#define BM 128
#define BN 64
#define BK 32
#define LDA 40               // padded LDS leading dim (elems); 40*2=80B = 5*16B aligned
#define LDB 40

typedef __attribute__((ext_vector_type(8))) __bf16 bf16x8;
typedef __attribute__((ext_vector_type(4))) float f32x4;

__device__ inline unsigned short f2bf(float f) {
    unsigned u = __float_as_uint(f);
    u += 0x7FFFu + ((u >> 16) & 1u);   // round-to-nearest-even
    return (unsigned short)(u >> 16);
}

// ---------------- x -> bf16 ----------------
__global__ __launch_bounds__(256) void cvt_x_kernel(const float* __restrict__ x,
                                                    unsigned short* __restrict__ xb) {
    int i = (blockIdx.x * 256 + threadIdx.x) * 4;
    float4 v = *(const float4*)(x + i);
    ushort4 o;
    o.x = f2bf(v.x); o.y = f2bf(v.y); o.z = f2bf(v.z); o.w = f2bf(v.w);
    *(ushort4*)(xb + i) = o;
}

// ---------------- gating: fp32 logits + grouped top-k ----------------
__global__ __launch_bounds__(64) void gate_kernel(const float* __restrict__ x,
                                                  const float* __restrict__ gate_w,
                                                  int* __restrict__ counts,
                                                  int* __restrict__ topk_idx,
                                                  float* __restrict__ topk_w) {
    int t = blockIdx.x;
    int e = threadIdx.x;           // 64 threads, one expert each
    const float4* xr = (const float4*)(x + (size_t)t * H_);
    const float4* wr = (const float4*)(gate_w + (size_t)e * H_);
    float acc = 0.0f;
    for (int i = 0; i < H_ / 4; ++i) {
        float4 a = xr[i], b = wr[i];
        acc += a.x * b.x + a.y * b.y + a.z * b.z + a.w * b.w;
    }
    __shared__ float lg[E_];
    lg[e] = acc;
    __syncthreads();
    if (e == 0) {
        // per-group top-4 -> 32 candidates in (group, rank) order
        float cv[GRP * TKG];
        int   ce[GRP * TKG];
        for (int g = 0; g < GRP; ++g) {
            unsigned used = 0;
            for (int r = 0; r < TKG; ++r) {
                float best = -INFINITY; int bi = 0;
                for (int j = 0; j < GSIZE; ++j) {
                    if (used & (1u << j)) continue;
                    float v = lg[g * GSIZE + j];
                    if (v > best) { best = v; bi = j; }   // strict >: lower index wins ties
                }
                used |= 1u << bi;
                cv[g * TKG + r] = best;
                ce[g * TKG + r] = g * GSIZE + bi;
            }
        }
        // top-8 of the 32 candidates
        float sv[KSEL]; int si[KSEL];
        unsigned used = 0;
        float sum = 0.0f;
        for (int r = 0; r < KSEL; ++r) {
            float best = -INFINITY; int bi = 0;
            for (int j = 0; j < GRP * TKG; ++j) {
                if (used & (1u << j)) continue;
                if (cv[j] > best) { best = cv[j]; bi = j; }
            }
            used |= 1u << bi;
            sv[r] = best; si[r] = ce[bi];
            sum += best;
        }
        float inv = 1.0f / (sum + 1e-20f);
        for (int r = 0; r < KSEL; ++r) {
            topk_idx[t * KSEL + r] = si[r];
            topk_w[t * KSEL + r] = sv[r] * inv;
            atomicAdd(&counts[si[r]], 1);
        }
    }
}

// ---------------- prefix sum over 66 job counts ----------------
__global__ void prefix_kernel(int* __restrict__ counts, int* __restrict__ offsets,
                              int* __restrict__ cursor) {
    if (threadIdx.x == 0) {
        counts[E_] = T_;
        counts[E_ + 1] = T_;
        int acc = 0;
        for (int j = 0; j < NJOB; ++j) {
            offsets[j] = acc;
            cursor[j] = acc;
            acc += counts[j];
        }
        offsets[NJOB] = acc;   // == ROWS_TOTAL
    }
}

// ---------------- scatter (token, weight) pairs into compact per-job segments ----------------
__global__ __launch_bounds__(256) void place_kernel(const int* __restrict__ topk_idx,
                                                    const float* __restrict__ topk_w,
                                                    const int* __restrict__ offsets,
                                                    int* __restrict__ cursor,
                                                    int* __restrict__ row_token,
                                                    float* __restrict__ row_w) {
    int p = blockIdx.x * 256 + threadIdx.x;
    if (p < T_ * KSEL) {
        int t = p >> 3;
        int e = topk_idx[p];
        int slot = atomicAdd(&cursor[e], 1);
        row_token[slot] = t;
        row_w[slot] = topk_w[p];
    } else if (p < T_ * KSEL + S_ * T_) {
        int q = p - T_ * KSEL;
        int s = q >> 10;          // / T_
        int t = q & (T_ - 1);
        int slot = offsets[E_ + s] + t;
        row_token[slot] = t;
        row_w[slot] = 1.0f;
    }
}

// ---------------- grouped GEMM 1: hidden = silu(x@Wg) * (x@Wu), bf16 MFMA ----------------
__global__ __launch_bounds__(256) void gateup_kernel(const unsigned short* __restrict__ xb,
                                                     const float* __restrict__ w_gu,
                                                     const float* __restrict__ s_gu,
                                                     const int* __restrict__ offsets,
                                                     const int* __restrict__ row_token,
                                                     unsigned short* __restrict__ hidden) {
    int job = blockIdx.x, mt = blockIdx.y, nt = blockIdx.z;
    int seg = offsets[job];
    int cnt = offsets[job + 1] - seg;
    int m0 = mt * BM;
    if (m0 >= cnt) return;
    const float* Bp = (job < E_) ? (w_gu + (size_t)job * H_ * (2 * I_))
                                 : (s_gu + (size_t)(job - E_) * H_ * (2 * I_));
    int n0 = nt * BN;

    __shared__ unsigned short As[BM * LDA];
    __shared__ unsigned short Bg[BN * LDB];
    __shared__ unsigned short Bu[BN * LDB];

    int tid = threadIdx.x;
    int wv = tid >> 6;
    int lane = tid & 63;
    int lrow = lane & 15;
    int lq = lane >> 4;

    // A staging map: chunk c in {tid, tid+256}: row=c>>2, kc=(c&3)*8
    int arow0 = tid >> 2;
    int akc = (tid & 3) * 8;
    int arow1 = (tid + 256) >> 2;
    int gidx0 = seg + m0 + arow0; if (gidx0 > ROWS_TOTAL - 1) gidx0 = ROWS_TOTAL - 1;
    int gidx1 = seg + m0 + arow1; if (gidx1 > ROWS_TOTAL - 1) gidx1 = ROWS_TOTAL - 1;
    const unsigned short* ap0 = xb + (size_t)row_token[gidx0] * H_;
    const unsigned short* ap1 = xb + (size_t)row_token[gidx1] * H_;

    // B staging map: chunk c in {tid, tid+256}: k=c>>4, nc=(c&15)*4
    int bk0 = tid >> 4;
    int bnc = (tid & 15) * 4;
    int bk1 = bk0 + 16;

    f32x4 accg[2][4], accu[2][4];
    f32x4 zero = {0.f, 0.f, 0.f, 0.f};
#pragma unroll
    for (int a = 0; a < 2; ++a)
#pragma unroll
        for (int b = 0; b < 4; ++b) { accg[a][b] = zero; accu[a][b] = zero; }

    for (int k0 = 0; k0 < H_; k0 += BK) {
        *(uint4*)&As[arow0 * LDA + akc] = *(const uint4*)(ap0 + k0 + akc);
        *(uint4*)&As[arow1 * LDA + akc] = *(const uint4*)(ap1 + k0 + akc);

        float4 vg0 = *(const float4*)(Bp + (size_t)(k0 + bk0) * (2 * I_) + n0 + bnc);
        float4 vg1 = *(const float4*)(Bp + (size_t)(k0 + bk1) * (2 * I_) + n0 + bnc);
        float4 vu0 = *(const float4*)(Bp + (size_t)(k0 + bk0) * (2 * I_) + (I_ + n0) + bnc);
        float4 vu1 = *(const float4*)(Bp + (size_t)(k0 + bk1) * (2 * I_) + (I_ + n0) + bnc);
        Bg[(bnc + 0) * LDB + bk0] = f2bf(vg0.x);
        Bg[(bnc + 1) * LDB + bk0] = f2bf(vg0.y);
        Bg[(bnc + 2) * LDB + bk0] = f2bf(vg0.z);
        Bg[(bnc + 3) * LDB + bk0] = f2bf(vg0.w);
        Bg[(bnc + 0) * LDB + bk1] = f2bf(vg1.x);
        Bg[(bnc + 1) * LDB + bk1] = f2bf(vg1.y);
        Bg[(bnc + 2) * LDB + bk1] = f2bf(vg1.z);
        Bg[(bnc + 3) * LDB + bk1] = f2bf(vg1.w);
        Bu[(bnc + 0) * LDB + bk0] = f2bf(vu0.x);
        Bu[(bnc + 1) * LDB + bk0] = f2bf(vu0.y);
        Bu[(bnc + 2) * LDB + bk0] = f2bf(vu0.z);
        Bu[(bnc + 3) * LDB + bk0] = f2bf(vu0.w);
        Bu[(bnc + 0) * LDB + bk1] = f2bf(vu1.x);
        Bu[(bnc + 1) * LDB + bk1] = f2bf(vu1.y);
        Bu[(bnc + 2) * LDB + bk1] = f2bf(vu1.z);
        Bu[(bnc + 3) * LDB + bk1] = f2bf(vu1.w);
        __syncthreads();

#pragma unroll
        for (int rb = 0; rb < 2; ++rb) {
            bf16x8 af = *(const bf16x8*)&As[(wv * 32 + rb * 16 + lrow) * LDA + lq * 8];
#pragma unroll
            for (int cb = 0; cb < 4; ++cb) {
                bf16x8 bg = *(const bf16x8*)&Bg[(cb * 16 + lrow) * LDB + lq * 8];
                bf16x8 bu = *(const bf16x8*)&Bu[(cb * 16 + lrow) * LDB + lq * 8];
                accg[rb][cb] = __builtin_amdgcn_mfma_f32_16x16x32_bf16(af, bg, accg[rb][cb], 0, 0, 0);
                accu[rb][cb] = __builtin_amdgcn_mfma_f32_16x16x32_bf16(af, bu, accu[rb][cb], 0, 0, 0);
            }
        }
        __syncthreads();
    }

#pragma unroll
    for (int rb = 0; rb < 2; ++rb) {
#pragma unroll
        for (int cb = 0; cb < 4; ++cb) {
#pragma unroll
            for (int r = 0; r < 4; ++r) {
                int row = wv * 32 + rb * 16 + lq * 4 + r;
                if (m0 + row < cnt) {
                    float g = accg[rb][cb][r];
                    float u = accu[rb][cb][r];
                    float h = g / (1.0f + __expf(-g)) * u;
                    int col = n0 + cb * 16 + lrow;
                    hidden[(size_t)(seg + m0 + row) * I_ + col] = f2bf(h);
                }
            }
        }
    }
}

// ---------------- grouped GEMM 2: out += w * (hidden @ Wd), bf16 MFMA ----------------
__global__ __launch_bounds__(256) void down_kernel(const unsigned short* __restrict__ hidden,
                                                   const float* __restrict__ w_d,
                                                   const float* __restrict__ s_d,
                                                   const int* __restrict__ offsets,
                                                   const int* __restrict__ row_token,
                                                   const float* __restrict__ row_w,
                                                   float* __restrict__ out) {
    int job = blockIdx.x, mt = blockIdx.y, nt = blockIdx.z;
    int seg = offsets[job];
    int cnt = offsets[job + 1] - seg;
    int m0 = mt * BM;
    if (m0 >= cnt) return;
    const float* Bp = (job < E_) ? (w_d + (size_t)job * I_ * H_)
                                 : (s_d + (size_t)(job - E_) * I_ * H_);
    int n0 = nt * BN;

    __shared__ unsigned short As[BM * LDA];
    __shared__ unsigned short Bs[BN * LDB];

    int tid = threadIdx.x;
    int wv = tid >> 6;
    int lane = tid & 63;
    int lrow = lane & 15;
    int lq = lane >> 4;

    int arow0 = tid >> 2;
    int akc = (tid & 3) * 8;
    int arow1 = (tid + 256) >> 2;
    int gidx0 = seg + m0 + arow0; if (gidx0 > ROWS_TOTAL - 1) gidx0 = ROWS_TOTAL - 1;
    int gidx1 = seg + m0 + arow1; if (gidx1 > ROWS_TOTAL - 1) gidx1 = ROWS_TOTAL - 1;
    const unsigned short* ap0 = hidden + (size_t)gidx0 * I_;
    const unsigned short* ap1 = hidden + (size_t)gidx1 * I_;

    int bk0 = tid >> 4;
    int bnc = (tid & 15) * 4;
    int bk1 = bk0 + 16;

    f32x4 acc[2][4];
    f32x4 zero = {0.f, 0.f, 0.f, 0.f};
#pragma unroll
    for (int a = 0; a < 2; ++a)
#pragma unroll
        for (int b = 0; b < 4; ++b) acc[a][b] = zero;

    for (int k0 = 0; k0 < I_; k0 += BK) {
        *(uint4*)&As[arow0 * LDA + akc] = *(const uint4*)(ap0 + k0 + akc);
        *(uint4*)&As[arow1 * LDA + akc] = *(const uint4*)(ap1 + k0 + akc);

        float4 v0 = *(const float4*)(Bp + (size_t)(k0 + bk0) * H_ + n0 + bnc);
        float4 v1 = *(const float4*)(Bp + (size_t)(k0 + bk1) * H_ + n0 + bnc);
        Bs[(bnc + 0) * LDB + bk0] = f2bf(v0.x);
        Bs[(bnc + 1) * LDB + bk0] = f2bf(v0.y);
        Bs[(bnc + 2) * LDB + bk0] = f2bf(v0.z);
        Bs[(bnc + 3) * LDB + bk0] = f2bf(v0.w);
        Bs[(bnc + 0) * LDB + bk1] = f2bf(v1.x);
        Bs[(bnc + 1) * LDB + bk1] = f2bf(v1.y);
        Bs[(bnc + 2) * LDB + bk1] = f2bf(v1.z);
        Bs[(bnc + 3) * LDB + bk1] = f2bf(v1.w);
        __syncthreads();

#pragma unroll
        for (int rb = 0; rb < 2; ++rb) {
            bf16x8 af = *(const bf16x8*)&As[(wv * 32 + rb * 16 + lrow) * LDA + lq * 8];
#pragma unroll
            for (int cb = 0; cb < 4; ++cb) {
                bf16x8 bf = *(const bf16x8*)&Bs[(cb * 16 + lrow) * LDB + lq * 8];
                acc[rb][cb] = __builtin_amdgcn_mfma_f32_16x16x32_bf16(af, bf, acc[rb][cb], 0, 0, 0);
            }
        }
        __syncthreads();
    }

#pragma unroll
    for (int rb = 0; rb < 2; ++rb) {
#pragma unroll
        for (int cb = 0; cb < 4; ++cb) {
#pragma unroll
            for (int r = 0; r < 4; ++r) {
                int row = wv * 32 + rb * 16 + lq * 4 + r;
                if (m0 + row < cnt) {
                    int gi = seg + m0 + row;
                    float v = acc[rb][cb][r] * row_w[gi];
                    atomicAdd(&out[(size_t)row_token[gi] * H_ + n0 + cb * 16 + lrow], v);
                }
            }
        }
    }
}

extern "C" void kernel_launch(void* const* d_in, const int* in_sizes, int n_in,
                              void* d_out, int out_size, void* d_ws, size_t ws_size,
                              hipStream_t stream) {
    const float* x      = (const float*)d_in[0];
    const float* gate_w = (const float*)d_in[1];
    const float* w_gu   = (const float*)d_in[2];
    const float* w_d    = (const float*)d_in[3];
    const float* s_gu   = (const float*)d_in[4];
    const float* s_d    = (const float*)d_in[5];
    float* out = (float*)d_out;

    char* ws = (char*)d_ws;
    size_t off = 0;
    auto carve = [&](size_t bytes) -> void* {
        void* p = ws + off;
        off += (bytes + 255) & ~(size_t)255;
        return p;
    };
    int* counts            = (int*)carve(NJOB * 4);
    int* offsets           = (int*)carve((NJOB + 1) * 4);
    int* cursor            = (int*)carve(NJOB * 4);
    int* topk_idx          = (int*)carve(T_ * KSEL * 4);
    float* topk_w          = (float*)carve(T_ * KSEL * 4);
    int* row_token         = (int*)carve(ROWS_TOTAL * 4);
    float* row_w           = (float*)carve(ROWS_TOTAL * 4);
    unsigned short* xb     = (unsigned short*)carve((size_t)T_ * H_ * 2);
    unsigned short* hidden = (unsigned short*)carve((size_t)ROWS_TOTAL * I_ * 2);

    hipMemsetAsync(out, 0, (size_t)T_ * H_ * 4, stream);
    hipMemsetAsync(counts, 0, NJOB * 4, stream);

    cvt_x_kernel<<<(T_ * H_ / 4) / 256, 256, 0, stream>>>(x, xb);
    gate_kernel<<<T_, 64, 0, stream>>>(x, gate_w, counts, topk_idx, topk_w);
    prefix_kernel<<<1, 64, 0, stream>>>(counts, offsets, cursor);
    place_kernel<<<(ROWS_TOTAL + 255) / 256, 256, 0, stream>>>(topk_idx, topk_w, offsets,
                                                               cursor, row_token, row_w);
    gateup_kernel<<<dim3(NJOB, T_ / BM, I_ / BN), 256, 0, stream>>>(xb, w_gu, s_gu, offsets,
                                                                    row_token, hidden);
    down_kernel<<<dim3(NJOB, T_ / BM, H_ / BN), 256, 0, stream>>>(hidden, w_d, s_d, offsets,
                                                                  row_token, row_w, out);
}